// Round 1
// baseline (6858.980 us; speedup 1.0000x reference)
//
#include <hip/hip_runtime.h>
#include <math.h>

#define BB 2
#define CC 272
#define GG 17
#define CG 16
#define HH 128
#define WW 128
#define HWX (HH*WW)
#define AFFC 102   // 6*G

// regular grid taps (row-major 3x3): KY[t] = t/3-1, KX[t] = t%3-1

// ---------------- Kernel A: grouped 3x3 offset-transform conv ----------------
// one thread per output element of aff (B,102,H,W); o is uniform per block
__global__ __launch_bounds__(256) void aff_conv_kernel(
    const float* __restrict__ x, const float* __restrict__ tm_w,
    const float* __restrict__ tm_b, float* __restrict__ aff)
{
    int idx = blockIdx.x * 256 + threadIdx.x;
    int w = idx & (WW - 1);
    int h = (idx >> 7) & (HH - 1);
    int o = (idx >> 14) % AFFC;
    int b = idx / (AFFC * HWX);
    int ig = o / 6;                       // conv input group (torch-faithful: != deform group)
    const float* xb = x + (size_t)(b * CC + ig * CG) * HWX;
    const float* wp = tm_w + (size_t)o * (CG * 9);
    float acc = 0.f;
#pragma unroll
    for (int ky = 0; ky < 3; ++ky) {
        int hy = h + ky - 1;
        bool vy = (hy >= 0) && (hy < HH);
#pragma unroll
        for (int kx = 0; kx < 3; ++kx) {
            int wx = w + kx - 1;
            bool v = vy && (wx >= 0) && (wx < WW);
            if (v) {
                const float* px = xb + hy * WW + wx;
#pragma unroll
                for (int c = 0; c < CG; ++c)
                    acc = fmaf(px[c * HWX], wp[c * 9 + ky * 3 + kx], acc);
            }
        }
    }
    aff[idx] = acc + tm_b[o];
}

// ---------------- Kernel C: deformable grouped conv + BN-stat partials -------
// block = 16x16 pixel tile for one (b,g); each thread computes 16 out channels
__global__ __launch_bounds__(256) void deform_kernel(
    const float* __restrict__ x, const float* __restrict__ dc_w,
    const float* __restrict__ aff_buf, float* __restrict__ pre,
    float* __restrict__ stat_sum, float* __restrict__ stat_sqs)
{
    __shared__ float lw[CG * 9 * CG];     // [c][t][oc]
    __shared__ float red[CG][4][2];

    const int b = blockIdx.z / GG;
    const int g = blockIdx.z % GG;
    const int tid = threadIdx.y * 16 + threadIdx.x;

    // stage conv weights for this group: dc_w[(g*16+oc)][c][t] -> lw[(c*9+t)*16+oc]
    for (int i = tid; i < CG * CG * 9; i += 256) {
        int oc = i / 144, rem = i % 144;
        int c = rem / 9, t = rem % 9;
        lw[(c * 9 + t) * CG + oc] = dc_w[(size_t)(g * CG + oc) * 144 + rem];
    }
    __syncthreads();

    const int h = blockIdx.y * 16 + threadIdx.y;
    const int w = blockIdx.x * 16 + threadIdx.x;

    // 2x3 affine params for this pixel/group; channel = 51*i + 17*j + g
    float a[2][3];
#pragma unroll
    for (int i = 0; i < 2; ++i)
#pragma unroll
        for (int j = 0; j < 3; ++j)
            a[i][j] = aff_buf[(size_t)(b * AFFC + (i * 51 + j * 17 + g)) * HWX + h * WW + w];

    const float* xb = x + (size_t)(b * CC + g * CG) * HWX;

    float acc[CG];
#pragma unroll
    for (int oc = 0; oc < CG; ++oc) acc[oc] = 0.f;

    static constexpr float KYf[9] = {-1,-1,-1, 0,0,0, 1,1,1};
    static constexpr float KXf[9] = {-1, 0, 1,-1,0,1,-1,0,1};

#pragma unroll
    for (int t = 0; t < 9; ++t) {
        // torch-faithful interleave: dy = flat[2t], dx = flat[2t+1], flat[e=i*9+k]
        const int e0 = 2 * t, e1 = 2 * t + 1;
        const int i0 = e0 / 9, k0 = e0 % 9, i1 = e1 / 9, k1 = e1 % 9;
        float dy = a[i0][0] * KYf[k0] + a[i0][1] * KXf[k0] + a[i0][2];
        float dx = a[i1][0] * KYf[k1] + a[i1][1] * KXf[k1] + a[i1][2];
        float py = (float)(h + t / 3 - 1) + dy;
        float px = (float)(w + t % 3 - 1) + dx;
        float y0f = floorf(py), x0f = floorf(px);
        float wy = py - y0f, wx = px - x0f;
        int y0 = (int)y0f, x0 = (int)x0f;
        int y1 = y0 + 1, x1 = x0 + 1;
        bool vy0 = (y0 >= 0) && (y0 < HH), vy1 = (y1 >= 0) && (y1 < HH);
        bool vx0 = (x0 >= 0) && (x0 < WW), vx1 = (x1 >= 0) && (x1 < WW);
        int y0c = min(max(y0, 0), HH - 1), y1c = min(max(y1, 0), HH - 1);
        int x0c = min(max(x0, 0), WW - 1), x1c = min(max(x1, 0), WW - 1);
        float w00 = (vy0 && vx0) ? (1.f - wy) * (1.f - wx) : 0.f;
        float w01 = (vy0 && vx1) ? (1.f - wy) * wx : 0.f;
        float w10 = (vy1 && vx0) ? wy * (1.f - wx) : 0.f;
        float w11 = (vy1 && vx1) ? wy * wx : 0.f;
        int l00 = y0c * WW + x0c, l01 = y0c * WW + x1c;
        int l10 = y1c * WW + x0c, l11 = y1c * WW + x1c;
#pragma unroll
        for (int c = 0; c < CG; ++c) {
            const float* p = xb + c * HWX;
            float s = w00 * p[l00] + w01 * p[l01] + w10 * p[l10] + w11 * p[l11];
#pragma unroll
            for (int oc = 0; oc < CG; ++oc)
                acc[oc] = fmaf(s, lw[(c * 9 + t) * CG + oc], acc[oc]);
        }
    }

    // write pre-BN output + block-level BN partial sums
    const int lane = tid & 63, wave = tid >> 6;
#pragma unroll
    for (int oc = 0; oc < CG; ++oc) {
        pre[(size_t)(b * CC + g * CG + oc) * HWX + h * WW + w] = acc[oc];
        float s = acc[oc], q = acc[oc] * acc[oc];
#pragma unroll
        for (int off = 32; off > 0; off >>= 1) {
            s += __shfl_down(s, off);
            q += __shfl_down(q, off);
        }
        if (lane == 0) { red[oc][wave][0] = s; red[oc][wave][1] = q; }
    }
    __syncthreads();
    if (tid < CG) {
        float s = red[tid][0][0] + red[tid][1][0] + red[tid][2][0] + red[tid][3][0];
        float q = red[tid][0][1] + red[tid][1][1] + red[tid][2][1] + red[tid][3][1];
        int ch = g * CG + tid;
        atomicAdd(&stat_sum[ch], s);
        atomicAdd(&stat_sqs[ch], q);
    }
}

// ---------------- Kernel D: BN (training stats) + residual ReLU --------------
__global__ __launch_bounds__(256) void bn_res_relu_kernel(
    const float* __restrict__ pre, const float* __restrict__ x,
    const float* __restrict__ stat_sum, const float* __restrict__ stat_sqs,
    const float* __restrict__ gamma, const float* __restrict__ beta,
    float* __restrict__ out)
{
    int idx = blockIdx.x * 256 + threadIdx.x;
    int c = (idx >> 14) % CC;
    const float n = (float)(BB * HWX);
    float mean = stat_sum[c] / n;
    float var = stat_sqs[c] / n - mean * mean;
    float inv = rsqrtf(var + 1e-5f);
    float v = (pre[idx] - mean) * inv * gamma[c] + beta[c] + x[idx];
    out[idx] = fmaxf(v, 0.f);
}

extern "C" void kernel_launch(void* const* d_in, const int* in_sizes, int n_in,
                              void* d_out, int out_size, void* d_ws, size_t ws_size,
                              hipStream_t stream)
{
    const float* x     = (const float*)d_in[0];
    const float* tm_w  = (const float*)d_in[1];
    const float* tm_b  = (const float*)d_in[2];
    const float* dc_w  = (const float*)d_in[3];
    const float* gamma = (const float*)d_in[4];
    const float* beta  = (const float*)d_in[5];
    float* out = (float*)d_out;

    float* ws = (float*)d_ws;
    float* stat_sum = ws;                       // 272 floats
    float* stat_sqs = ws + CC;                  // 272 floats
    float* aff = ws + 1024;                     // B*102*HW floats
    float* pre = aff + (size_t)BB * AFFC * HWX; // B*C*HW floats

    hipMemsetAsync(stat_sum, 0, 2 * CC * sizeof(float), stream);

    aff_conv_kernel<<<dim3(BB * AFFC * HWX / 256), dim3(256), 0, stream>>>(x, tm_w, tm_b, aff);
    deform_kernel<<<dim3(WW / 16, HH / 16, BB * GG), dim3(16, 16), 0, stream>>>(
        x, dc_w, aff, pre, stat_sum, stat_sqs);
    bn_res_relu_kernel<<<dim3(BB * CC * HWX / 256), dim3(256), 0, stream>>>(
        pre, x, stat_sum, stat_sqs, gamma, beta, out);
}

// Round 2
// 337.323 us; speedup vs baseline: 20.3335x; 20.3335x over previous
//
#include <hip/hip_runtime.h>
#include <math.h>

#define BB 2
#define CC 272
#define GG 17
#define CG 16
#define HH 128
#define WW 128
#define HWX (HH*WW)
#define AFFC 102   // 6*G

// ---------------- Kernel A: grouped 3x3 offset-transform conv ----------------
// one thread per output element of aff (B,102,H,W); o is uniform per block
__global__ __launch_bounds__(256) void aff_conv_kernel(
    const float* __restrict__ x, const float* __restrict__ tm_w,
    const float* __restrict__ tm_b, float* __restrict__ aff)
{
    int idx = blockIdx.x * 256 + threadIdx.x;
    int w = idx & (WW - 1);
    int h = (idx >> 7) & (HH - 1);
    int o = (idx >> 14) % AFFC;
    int b = idx / (AFFC * HWX);
    int ig = o / 6;                       // conv input group (torch-faithful: != deform group)
    const float* xb = x + (size_t)(b * CC + ig * CG) * HWX;
    const float* wp = tm_w + (size_t)o * (CG * 9);
    float acc = 0.f;
#pragma unroll
    for (int ky = 0; ky < 3; ++ky) {
        int hy = h + ky - 1;
        bool vy = (hy >= 0) && (hy < HH);
#pragma unroll
        for (int kx = 0; kx < 3; ++kx) {
            int wx = w + kx - 1;
            bool v = vy && (wx >= 0) && (wx < WW);
            if (v) {
                const float* px = xb + hy * WW + wx;
#pragma unroll
                for (int c = 0; c < CG; ++c)
                    acc = fmaf(px[c * HWX], wp[c * 9 + ky * 3 + kx], acc);
            }
        }
    }
    aff[idx] = acc + tm_b[o];
}

// ---------------- Kernel C: deformable grouped conv + BN-stat partials -------
// block = 16x16 pixel tile for one (b,g); each thread computes 16 out channels
__global__ __launch_bounds__(256, 4) void deform_kernel(
    const float* __restrict__ x, const float* __restrict__ dc_w,
    const float* __restrict__ aff_buf, float* __restrict__ pre,
    float* __restrict__ stat_sum, float* __restrict__ stat_sqs)
{
    __shared__ float lw[CG * 9 * CG];     // [c][t][oc], oc contiguous (float4-aligned)
    __shared__ float red[CG][4][2];

    const int b = blockIdx.z / GG;
    const int g = blockIdx.z % GG;
    const int tid = threadIdx.y * 16 + threadIdx.x;

    // stage conv weights for this group: dc_w[(g*16+oc)][c][t] -> lw[(c*9+t)*16+oc]
    for (int i = tid; i < CG * CG * 9; i += 256) {
        int oc = i / 144, rem = i % 144;
        lw[rem * CG + oc] = dc_w[(size_t)(g * CG + oc) * 144 + rem];
    }
    __syncthreads();

    const int h = blockIdx.y * 16 + threadIdx.y;
    const int w = blockIdx.x * 16 + threadIdx.x;

    // 2x3 affine params for this pixel/group; channel = 51*i + 17*j + g
    float a00 = aff_buf[(size_t)(b * AFFC + (0 * 51 + 0 * 17 + g)) * HWX + h * WW + w];
    float a01 = aff_buf[(size_t)(b * AFFC + (0 * 51 + 1 * 17 + g)) * HWX + h * WW + w];
    float a02 = aff_buf[(size_t)(b * AFFC + (0 * 51 + 2 * 17 + g)) * HWX + h * WW + w];
    float a10 = aff_buf[(size_t)(b * AFFC + (1 * 51 + 0 * 17 + g)) * HWX + h * WW + w];
    float a11 = aff_buf[(size_t)(b * AFFC + (1 * 51 + 1 * 17 + g)) * HWX + h * WW + w];
    float a12 = aff_buf[(size_t)(b * AFFC + (1 * 51 + 2 * 17 + g)) * HWX + h * WW + w];

    const float* xb = x + (size_t)(b * CC + g * CG) * HWX;

    float acc[CG];
#pragma unroll
    for (int oc = 0; oc < CG; ++oc) acc[oc] = 0.f;

#pragma unroll 1
    for (int t = 0; t < 9; ++t) {
        // torch-faithful interleave: dy = flat[2t], dx = flat[2t+1], flat[e=i*9+k]
        // tap constants computed arithmetically (no indexed const arrays -> no scratch)
        int e0 = 2 * t, e1 = 2 * t + 1;
        int i0 = e0 / 9, k0 = e0 % 9, i1 = e1 / 9, k1 = e1 % 9;
        float ky0 = (float)(k0 / 3 - 1), kx0 = (float)(k0 % 3 - 1);
        float ky1 = (float)(k1 / 3 - 1), kx1 = (float)(k1 % 3 - 1);
        float b0y = i0 ? a10 : a00, b0x = i0 ? a11 : a01, b0c = i0 ? a12 : a02;
        float b1y = i1 ? a10 : a00, b1x = i1 ? a11 : a01, b1c = i1 ? a12 : a02;
        float dy = b0y * ky0 + b0x * kx0 + b0c;
        float dx = b1y * ky1 + b1x * kx1 + b1c;
        float py = (float)(h + t / 3 - 1) + dy;
        float px = (float)(w + t % 3 - 1) + dx;
        float y0f = floorf(py), x0f = floorf(px);
        float wy = py - y0f, wx = px - x0f;
        int y0 = (int)y0f, x0 = (int)x0f;
        int y1 = y0 + 1, x1 = x0 + 1;
        bool vy0 = (y0 >= 0) && (y0 < HH), vy1 = (y1 >= 0) && (y1 < HH);
        bool vx0 = (x0 >= 0) && (x0 < WW), vx1 = (x1 >= 0) && (x1 < WW);
        int y0c = min(max(y0, 0), HH - 1), y1c = min(max(y1, 0), HH - 1);
        int x0c = min(max(x0, 0), WW - 1), x1c = min(max(x1, 0), WW - 1);
        float w00 = (vy0 && vx0) ? (1.f - wy) * (1.f - wx) : 0.f;
        float w01 = (vy0 && vx1) ? (1.f - wy) * wx : 0.f;
        float w10 = (vy1 && vx0) ? wy * (1.f - wx) : 0.f;
        float w11 = (vy1 && vx1) ? wy * wx : 0.f;
        const float* p00 = xb + y0c * WW + x0c;
        const float* p01 = xb + y0c * WW + x1c;
        const float* p10 = xb + y1c * WW + x0c;
        const float* p11 = xb + y1c * WW + x1c;
        const float4* wt = (const float4*)&lw[t * CG];

#pragma unroll 4
        for (int c = 0; c < CG; ++c) {
            float s = w00 * p00[c * HWX] + w01 * p01[c * HWX]
                    + w10 * p10[c * HWX] + w11 * p11[c * HWX];
            // weights for (c,t): 16 oc, uniform across lanes -> LDS broadcast as 4x float4
            const float4* wp = wt + c * (9 * CG / 4);
            float4 q0 = wp[0], q1 = wp[1], q2 = wp[2], q3 = wp[3];
            acc[0]  = fmaf(s, q0.x, acc[0]);  acc[1]  = fmaf(s, q0.y, acc[1]);
            acc[2]  = fmaf(s, q0.z, acc[2]);  acc[3]  = fmaf(s, q0.w, acc[3]);
            acc[4]  = fmaf(s, q1.x, acc[4]);  acc[5]  = fmaf(s, q1.y, acc[5]);
            acc[6]  = fmaf(s, q1.z, acc[6]);  acc[7]  = fmaf(s, q1.w, acc[7]);
            acc[8]  = fmaf(s, q2.x, acc[8]);  acc[9]  = fmaf(s, q2.y, acc[9]);
            acc[10] = fmaf(s, q2.z, acc[10]); acc[11] = fmaf(s, q2.w, acc[11]);
            acc[12] = fmaf(s, q3.x, acc[12]); acc[13] = fmaf(s, q3.y, acc[13]);
            acc[14] = fmaf(s, q3.z, acc[14]); acc[15] = fmaf(s, q3.w, acc[15]);
        }
    }

    // write pre-BN output + block-level BN partial sums
    const int lane = tid & 63, wave = tid >> 6;
#pragma unroll
    for (int oc = 0; oc < CG; ++oc) {
        pre[(size_t)(b * CC + g * CG + oc) * HWX + h * WW + w] = acc[oc];
    }
#pragma unroll 1
    for (int oc = 0; oc < CG; ++oc) {
        float s = acc[oc], q = acc[oc] * acc[oc];
#pragma unroll
        for (int off = 32; off > 0; off >>= 1) {
            s += __shfl_down(s, off);
            q += __shfl_down(q, off);
        }
        if (lane == 0) { red[oc][wave][0] = s; red[oc][wave][1] = q; }
    }
    __syncthreads();
    if (tid < CG) {
        float s = red[tid][0][0] + red[tid][1][0] + red[tid][2][0] + red[tid][3][0];
        float q = red[tid][0][1] + red[tid][1][1] + red[tid][2][1] + red[tid][3][1];
        int ch = g * CG + tid;
        atomicAdd(&stat_sum[ch], s);
        atomicAdd(&stat_sqs[ch], q);
    }
}

// ---------------- Kernel D: BN (training stats) + residual ReLU --------------
__global__ __launch_bounds__(256) void bn_res_relu_kernel(
    const float* __restrict__ pre, const float* __restrict__ x,
    const float* __restrict__ stat_sum, const float* __restrict__ stat_sqs,
    const float* __restrict__ gamma, const float* __restrict__ beta,
    float* __restrict__ out)
{
    int idx = blockIdx.x * 256 + threadIdx.x;
    int c = (idx >> 14) % CC;
    const float n = (float)(BB * HWX);
    float mean = stat_sum[c] / n;
    float var = stat_sqs[c] / n - mean * mean;
    float inv = rsqrtf(var + 1e-5f);
    float v = (pre[idx] - mean) * inv * gamma[c] + beta[c] + x[idx];
    out[idx] = fmaxf(v, 0.f);
}

extern "C" void kernel_launch(void* const* d_in, const int* in_sizes, int n_in,
                              void* d_out, int out_size, void* d_ws, size_t ws_size,
                              hipStream_t stream)
{
    const float* x     = (const float*)d_in[0];
    const float* tm_w  = (const float*)d_in[1];
    const float* tm_b  = (const float*)d_in[2];
    const float* dc_w  = (const float*)d_in[3];
    const float* gamma = (const float*)d_in[4];
    const float* beta  = (const float*)d_in[5];
    float* out = (float*)d_out;

    float* ws = (float*)d_ws;
    float* stat_sum = ws;                       // 272 floats
    float* stat_sqs = ws + CC;                  // 272 floats
    float* aff = ws + 1024;                     // B*102*HW floats
    float* pre = aff + (size_t)BB * AFFC * HWX; // B*C*HW floats

    hipMemsetAsync(stat_sum, 0, 2 * CC * sizeof(float), stream);

    aff_conv_kernel<<<dim3(BB * AFFC * HWX / 256), dim3(256), 0, stream>>>(x, tm_w, tm_b, aff);
    deform_kernel<<<dim3(WW / 16, HH / 16, BB * GG), dim3(16, 16), 0, stream>>>(
        x, dc_w, aff, pre, stat_sum, stat_sqs);
    bn_res_relu_kernel<<<dim3(BB * CC * HWX / 256), dim3(256), 0, stream>>>(
        pre, x, stat_sum, stat_sqs, gamma, beta, out);
}

// Round 3
// 209.090 us; speedup vs baseline: 32.8040x; 1.6133x over previous
//
#include <hip/hip_runtime.h>
#include <math.h>

#define BB 2
#define CC 272
#define GG 17
#define CG 16
#define HH 128
#define WW 128
#define HWX (HH*WW)
#define AFFC 102   // 6*G

// ---------------- Kernel T: NCHW -> (B,G,HW,16) channel-last transpose ------
__global__ __launch_bounds__(256) void transpose_kernel(
    const float* __restrict__ x, float* __restrict__ xt)
{
    __shared__ float tile[CG][WW + 1];
    const int h = blockIdx.x & (HH - 1);
    const int g = (blockIdx.x >> 7) % GG;
    const int b = blockIdx.x / (GG * HH);
    const int tid = threadIdx.x;
    const float* src = x + (size_t)(b * CC + g * CG) * HWX + h * WW;
    for (int i = tid; i < CG * WW; i += 256) {
        int c = i >> 7, w = i & (WW - 1);
        tile[c][w] = src[(size_t)c * HWX + w];
    }
    __syncthreads();
    float* dst = xt + ((size_t)(b * GG + g) * HWX + h * WW) * CG;
    for (int i = tid; i < CG * WW; i += 256) {
        int w = i >> 4, c = i & 15;
        dst[i] = tile[c][w];   // i = w*16 + c : fully coalesced
    }
}

// ---------------- Kernel A: grouped 3x3 offset-transform conv ----------------
// block = (b, ig); each thread: one pixel, computes the 6 outputs of group ig
__global__ __launch_bounds__(256) void aff_conv_kernel(
    const float* __restrict__ xt, const float* __restrict__ tm_w,
    const float* __restrict__ tm_b, float* __restrict__ aff)
{
    __shared__ float lw[6 * 9 * CG];      // [j][t][c], c contiguous
    const int ig = blockIdx.y;
    const int b = blockIdx.z;
    const int tid = threadIdx.x;
    for (int i = tid; i < 6 * 144; i += 256) {
        int j = i / 144, rem = i % 144;
        int c = rem / 9, t = rem % 9;
        lw[(j * 9 + t) * CG + c] = tm_w[(size_t)(ig * 6 + j) * 144 + rem];
    }
    __syncthreads();

    const int p = blockIdx.x * 256 + tid;
    const int h = p >> 7, w = p & (WW - 1);
    const float* xb = xt + (size_t)(b * GG + ig) * HWX * CG;

    float acc[6];
#pragma unroll
    for (int j = 0; j < 6; ++j) acc[j] = 0.f;

#pragma unroll 1
    for (int t = 0; t < 9; ++t) {
        int hy = h + t / 3 - 1;
        int wx = w + t % 3 - 1;
        float4 xv0 = {0,0,0,0}, xv1 = {0,0,0,0}, xv2 = {0,0,0,0}, xv3 = {0,0,0,0};
        if (hy >= 0 && hy < HH && wx >= 0 && wx < WW) {
            const float4* px = (const float4*)(xb + (size_t)(hy * WW + wx) * CG);
            xv0 = px[0]; xv1 = px[1]; xv2 = px[2]; xv3 = px[3];
        }
#pragma unroll
        for (int j = 0; j < 6; ++j) {
            const float4* wp = (const float4*)&lw[(j * 9 + t) * CG];
            float4 q0 = wp[0], q1 = wp[1], q2 = wp[2], q3 = wp[3];
            float a = acc[j];
            a = fmaf(xv0.x, q0.x, a); a = fmaf(xv0.y, q0.y, a);
            a = fmaf(xv0.z, q0.z, a); a = fmaf(xv0.w, q0.w, a);
            a = fmaf(xv1.x, q1.x, a); a = fmaf(xv1.y, q1.y, a);
            a = fmaf(xv1.z, q1.z, a); a = fmaf(xv1.w, q1.w, a);
            a = fmaf(xv2.x, q2.x, a); a = fmaf(xv2.y, q2.y, a);
            a = fmaf(xv2.z, q2.z, a); a = fmaf(xv2.w, q2.w, a);
            a = fmaf(xv3.x, q3.x, a); a = fmaf(xv3.y, q3.y, a);
            a = fmaf(xv3.z, q3.z, a); a = fmaf(xv3.w, q3.w, a);
            acc[j] = a;
        }
    }
#pragma unroll
    for (int j = 0; j < 6; ++j)
        aff[(size_t)(b * AFFC + ig * 6 + j) * HWX + p] = acc[j] + tm_b[ig * 6 + j];
}

// ---------------- Kernel C: deformable grouped conv + BN-stat partials -------
// block = 16x16 pixel tile for one (b,g); each thread computes 16 out channels
__global__ __launch_bounds__(256, 4) void deform_kernel(
    const float* __restrict__ xt, const float* __restrict__ dc_w,
    const float* __restrict__ aff_buf, float* __restrict__ pre,
    float* __restrict__ stat_sum, float* __restrict__ stat_sqs)
{
    __shared__ float lw[CG * 9 * CG];     // [(c*9+t)*16 + oc]
    __shared__ float red[CG][4][2];

    const int b = blockIdx.z / GG;
    const int g = blockIdx.z % GG;
    const int tid = threadIdx.y * 16 + threadIdx.x;

    for (int i = tid; i < CG * CG * 9; i += 256) {
        int oc = i / 144, rem = i % 144;
        lw[rem * CG + oc] = dc_w[(size_t)(g * CG + oc) * 144 + rem];
    }
    __syncthreads();

    const int h = blockIdx.y * 16 + threadIdx.y;
    const int w = blockIdx.x * 16 + threadIdx.x;

    // 2x3 affine params for this pixel/group; channel = 51*i + 17*j + g
    float a00 = aff_buf[(size_t)(b * AFFC + (0 * 51 + 0 * 17 + g)) * HWX + h * WW + w];
    float a01 = aff_buf[(size_t)(b * AFFC + (0 * 51 + 1 * 17 + g)) * HWX + h * WW + w];
    float a02 = aff_buf[(size_t)(b * AFFC + (0 * 51 + 2 * 17 + g)) * HWX + h * WW + w];
    float a10 = aff_buf[(size_t)(b * AFFC + (1 * 51 + 0 * 17 + g)) * HWX + h * WW + w];
    float a11 = aff_buf[(size_t)(b * AFFC + (1 * 51 + 1 * 17 + g)) * HWX + h * WW + w];
    float a12 = aff_buf[(size_t)(b * AFFC + (1 * 51 + 2 * 17 + g)) * HWX + h * WW + w];

    const float* xb = xt + (size_t)(b * GG + g) * HWX * CG;

    float acc[CG];
#pragma unroll
    for (int oc = 0; oc < CG; ++oc) acc[oc] = 0.f;

#pragma unroll 1
    for (int t = 0; t < 9; ++t) {
        // torch-faithful interleave: dy = flat[2t], dx = flat[2t+1], flat[e=i*9+k]
        int e0 = 2 * t, e1 = 2 * t + 1;
        int i0 = e0 / 9, k0 = e0 % 9, i1 = e1 / 9, k1 = e1 % 9;
        float ky0 = (float)(k0 / 3 - 1), kx0 = (float)(k0 % 3 - 1);
        float ky1 = (float)(k1 / 3 - 1), kx1 = (float)(k1 % 3 - 1);
        float b0y = i0 ? a10 : a00, b0x = i0 ? a11 : a01, b0c = i0 ? a12 : a02;
        float b1y = i1 ? a10 : a00, b1x = i1 ? a11 : a01, b1c = i1 ? a12 : a02;
        float dy = b0y * ky0 + b0x * kx0 + b0c;
        float dx = b1y * ky1 + b1x * kx1 + b1c;
        float py = (float)(h + t / 3 - 1) + dy;
        float px = (float)(w + t % 3 - 1) + dx;
        float y0f = floorf(py), x0f = floorf(px);
        float wy = py - y0f, wx = px - x0f;
        int y0 = (int)y0f, x0 = (int)x0f;
        int y1 = y0 + 1, x1 = x0 + 1;
        bool vy0 = (y0 >= 0) && (y0 < HH), vy1 = (y1 >= 0) && (y1 < HH);
        bool vx0 = (x0 >= 0) && (x0 < WW), vx1 = (x1 >= 0) && (x1 < WW);
        int y0c = min(max(y0, 0), HH - 1), y1c = min(max(y1, 0), HH - 1);
        int x0c = min(max(x0, 0), WW - 1), x1c = min(max(x1, 0), WW - 1);
        float w00 = (vy0 && vx0) ? (1.f - wy) * (1.f - wx) : 0.f;
        float w01 = (vy0 && vx1) ? (1.f - wy) * wx : 0.f;
        float w10 = (vy1 && vx0) ? wy * (1.f - wx) : 0.f;
        float w11 = (vy1 && vx1) ? wy * wx : 0.f;
        const float4* p00 = (const float4*)(xb + (size_t)(y0c * WW + x0c) * CG);
        const float4* p01 = (const float4*)(xb + (size_t)(y0c * WW + x1c) * CG);
        const float4* p10 = (const float4*)(xb + (size_t)(y1c * WW + x0c) * CG);
        const float4* p11 = (const float4*)(xb + (size_t)(y1c * WW + x1c) * CG);

#pragma unroll
        for (int c4 = 0; c4 < 4; ++c4) {
            float4 v00 = p00[c4], v01 = p01[c4], v10 = p10[c4], v11 = p11[c4];
            float se[4];
            se[0] = fmaf(w00, v00.x, fmaf(w01, v01.x, fmaf(w10, v10.x, w11 * v11.x)));
            se[1] = fmaf(w00, v00.y, fmaf(w01, v01.y, fmaf(w10, v10.y, w11 * v11.y)));
            se[2] = fmaf(w00, v00.z, fmaf(w01, v01.z, fmaf(w10, v10.z, w11 * v11.z)));
            se[3] = fmaf(w00, v00.w, fmaf(w01, v01.w, fmaf(w10, v10.w, w11 * v11.w)));
#pragma unroll
            for (int e = 0; e < 4; ++e) {
                float s = se[e];
                const float4* wp = (const float4*)&lw[((c4 * 4 + e) * 9 + t) * CG];
                float4 q0 = wp[0], q1 = wp[1], q2 = wp[2], q3 = wp[3];
                acc[0]  = fmaf(s, q0.x, acc[0]);  acc[1]  = fmaf(s, q0.y, acc[1]);
                acc[2]  = fmaf(s, q0.z, acc[2]);  acc[3]  = fmaf(s, q0.w, acc[3]);
                acc[4]  = fmaf(s, q1.x, acc[4]);  acc[5]  = fmaf(s, q1.y, acc[5]);
                acc[6]  = fmaf(s, q1.z, acc[6]);  acc[7]  = fmaf(s, q1.w, acc[7]);
                acc[8]  = fmaf(s, q2.x, acc[8]);  acc[9]  = fmaf(s, q2.y, acc[9]);
                acc[10] = fmaf(s, q2.z, acc[10]); acc[11] = fmaf(s, q2.w, acc[11]);
                acc[12] = fmaf(s, q3.x, acc[12]); acc[13] = fmaf(s, q3.y, acc[13]);
                acc[14] = fmaf(s, q3.z, acc[14]); acc[15] = fmaf(s, q3.w, acc[15]);
            }
        }
    }

    // write pre-BN output + block-level BN partial sums
    const int lane = tid & 63, wave = tid >> 6;
#pragma unroll
    for (int oc = 0; oc < CG; ++oc) {
        pre[(size_t)(b * CC + g * CG + oc) * HWX + h * WW + w] = acc[oc];
    }
#pragma unroll 1
    for (int oc = 0; oc < CG; ++oc) {
        float s = acc[oc], q = acc[oc] * acc[oc];
#pragma unroll
        for (int off = 32; off > 0; off >>= 1) {
            s += __shfl_down(s, off);
            q += __shfl_down(q, off);
        }
        if (lane == 0) { red[oc][wave][0] = s; red[oc][wave][1] = q; }
    }
    __syncthreads();
    if (tid < CG) {
        float s = red[tid][0][0] + red[tid][1][0] + red[tid][2][0] + red[tid][3][0];
        float q = red[tid][0][1] + red[tid][1][1] + red[tid][2][1] + red[tid][3][1];
        int ch = g * CG + tid;
        atomicAdd(&stat_sum[ch], s);
        atomicAdd(&stat_sqs[ch], q);
    }
}

// ---------------- Kernel D: BN (training stats) + residual ReLU (in-place) ---
__global__ __launch_bounds__(256) void bn_res_relu_kernel(
    const float* __restrict__ x,
    const float* __restrict__ stat_sum, const float* __restrict__ stat_sqs,
    const float* __restrict__ gamma, const float* __restrict__ beta,
    float* __restrict__ out)
{
    int idx = blockIdx.x * 256 + threadIdx.x;
    int c = (idx >> 14) % CC;
    const float n = (float)(BB * HWX);
    float mean = stat_sum[c] / n;
    float var = stat_sqs[c] / n - mean * mean;
    float inv = rsqrtf(var + 1e-5f);
    float v = (out[idx] - mean) * inv * gamma[c] + beta[c] + x[idx];
    out[idx] = fmaxf(v, 0.f);
}

extern "C" void kernel_launch(void* const* d_in, const int* in_sizes, int n_in,
                              void* d_out, int out_size, void* d_ws, size_t ws_size,
                              hipStream_t stream)
{
    const float* x     = (const float*)d_in[0];
    const float* tm_w  = (const float*)d_in[1];
    const float* tm_b  = (const float*)d_in[2];
    const float* dc_w  = (const float*)d_in[3];
    const float* gamma = (const float*)d_in[4];
    const float* beta  = (const float*)d_in[5];
    float* out = (float*)d_out;

    float* ws = (float*)d_ws;
    float* stat_sum = ws;                        // 272 floats
    float* stat_sqs = ws + CC;                   // 272 floats
    float* aff = ws + 1024;                      // B*102*HW floats
    float* xt  = aff + (size_t)BB * AFFC * HWX;  // B*G*HW*16 floats

    hipMemsetAsync(stat_sum, 0, 2 * CC * sizeof(float), stream);

    transpose_kernel<<<dim3(BB * GG * HH), dim3(256), 0, stream>>>(x, xt);
    aff_conv_kernel<<<dim3(HWX / 256, GG, BB), dim3(256), 0, stream>>>(xt, tm_w, tm_b, aff);
    deform_kernel<<<dim3(WW / 16, HH / 16, BB * GG), dim3(16, 16), 0, stream>>>(
        xt, dc_w, aff, out /*pre*/, stat_sum, stat_sqs);
    bn_res_relu_kernel<<<dim3(BB * CC * HWX / 256), dim3(256), 0, stream>>>(
        x, stat_sum, stat_sqs, gamma, beta, out);
}